// Round 1
// baseline (1277.892 us; speedup 1.0000x reference)
//
#include <hip/hip_runtime.h>
#include <math.h>

// ProbSparse attention (Informer-style), fp32.
// B=4, L=2048, D=1024, H=16, dk=64, u = int(ln(2048)) = 7.
#define Bc 4
#define Lc 2048
#define Dc 1024
#define Hc 16
#define DKc 64
#define Uc 7

// ---------------- projection GEMM: C[M,N] = A[M,K] @ W[N,K]^T + bias ----------------
__global__ __launch_bounds__(256) void proj_gemm(
    const float* __restrict__ A, const float* __restrict__ W,
    const float* __restrict__ bias, float* __restrict__ C,
    int M, int N, int K) {
  __shared__ float As[16][128];
  __shared__ float Ws[16][128];
  const int t = threadIdx.x;
  const int tx = t & 15, ty = t >> 4;
  const int bm = blockIdx.y * 128;
  const int bn = blockIdx.x * 128;
  float acc[8][8] = {};
  for (int k0 = 0; k0 < K; k0 += 16) {
#pragma unroll
    for (int i = 0; i < 2; ++i) {
      int f = t * 2 + i;        // float4 index 0..511
      int r = f >> 2;           // row 0..127
      int c = (f & 3) * 4;      // col 0..12
      float4 av = *(const float4*)(A + (size_t)(bm + r) * K + k0 + c);
      As[c + 0][r] = av.x; As[c + 1][r] = av.y; As[c + 2][r] = av.z; As[c + 3][r] = av.w;
      float4 wv = *(const float4*)(W + (size_t)(bn + r) * K + k0 + c);
      Ws[c + 0][r] = wv.x; Ws[c + 1][r] = wv.y; Ws[c + 2][r] = wv.z; Ws[c + 3][r] = wv.w;
    }
    __syncthreads();
#pragma unroll
    for (int kk = 0; kk < 16; ++kk) {
      float a[8], bb[8];
#pragma unroll
      for (int i = 0; i < 8; ++i) a[i] = As[kk][ty * 8 + i];
#pragma unroll
      for (int j = 0; j < 8; ++j) bb[j] = Ws[kk][tx * 8 + j];
#pragma unroll
      for (int i = 0; i < 8; ++i)
#pragma unroll
        for (int j = 0; j < 8; ++j)
          acc[i][j] = fmaf(a[i], bb[j], acc[i][j]);
    }
    __syncthreads();
  }
#pragma unroll
  for (int i = 0; i < 8; ++i) {
    int m = bm + ty * 8 + i;
#pragma unroll
    for (int j = 0; j < 8; ++j) {
      int n = bn + tx * 8 + j;
      C[(size_t)m * N + n] = acc[i][j] + bias[n];
    }
  }
}

// ------------- per-query max_k (Q . K) — never materializes scores -------------
// grid (L/128, H, B), block 256. Out: M[b,h,q] = 0.125 * max_k dot(Q[b,h,q,:],K[b,h,k,:])
__global__ __launch_bounds__(256) void rowmax_kernel(
    const float* __restrict__ Q, const float* __restrict__ K,
    float* __restrict__ Mout) {
  __shared__ float Qs[64][128];   // [d][q]
  __shared__ float Ks[16][128];   // [d][k]
  __shared__ float Red[128][17];
  const int t = threadIdx.x;
  const int tx = t & 15, ty = t >> 4;
  const int q0 = blockIdx.x * 128;
  const int h = blockIdx.y;
  const int b = blockIdx.z;
  const float* Qb = Q + (size_t)b * Lc * Dc + (size_t)h * DKc;
  const float* Kb = K + (size_t)b * Lc * Dc + (size_t)h * DKc;
  // load Q tile [128 q][64 d] transposed
#pragma unroll
  for (int i = 0; i < 8; ++i) {
    int f = t + i * 256;        // float4 id 0..2047
    int r = f >> 4;             // q row 0..127
    int c = (f & 15) * 4;       // d col
    float4 v = *(const float4*)(Qb + (size_t)(q0 + r) * Dc + c);
    Qs[c + 0][r] = v.x; Qs[c + 1][r] = v.y; Qs[c + 2][r] = v.z; Qs[c + 3][r] = v.w;
  }
  float rm[8];
#pragma unroll
  for (int i = 0; i < 8; ++i) rm[i] = -INFINITY;
  for (int kt = 0; kt < Lc; kt += 128) {
    float acc[8][8] = {};
    for (int d0 = 0; d0 < 64; d0 += 16) {
      __syncthreads();   // previous Ks consumers done (also guards Qs load 1st iter)
#pragma unroll
      for (int i = 0; i < 2; ++i) {
        int f = t * 2 + i;
        int r = f >> 2;
        int c = (f & 3) * 4;
        float4 v = *(const float4*)(Kb + (size_t)(kt + r) * Dc + d0 + c);
        Ks[c + 0][r] = v.x; Ks[c + 1][r] = v.y; Ks[c + 2][r] = v.z; Ks[c + 3][r] = v.w;
      }
      __syncthreads();
#pragma unroll
      for (int kk = 0; kk < 16; ++kk) {
        float a[8], bb[8];
#pragma unroll
        for (int i = 0; i < 8; ++i) a[i] = Qs[d0 + kk][ty * 8 + i];
#pragma unroll
        for (int j = 0; j < 8; ++j) bb[j] = Ks[kk][tx * 8 + j];
#pragma unroll
        for (int i = 0; i < 8; ++i)
#pragma unroll
          for (int j = 0; j < 8; ++j)
            acc[i][j] = fmaf(a[i], bb[j], acc[i][j]);
      }
    }
#pragma unroll
    for (int i = 0; i < 8; ++i)
#pragma unroll
      for (int j = 0; j < 8; ++j)
        rm[i] = fmaxf(rm[i], acc[i][j]);
  }
#pragma unroll
  for (int i = 0; i < 8; ++i) Red[ty * 8 + i][tx] = rm[i];
  __syncthreads();
  if (t < 128) {
    float v = Red[t][0];
#pragma unroll
    for (int x = 1; x < 16; ++x) v = fmaxf(v, Red[t][x]);
    Mout[((size_t)b * Hc + h) * Lc + q0 + t] = 0.125f * v;  // *2^-3 exact
  }
}

__global__ void zero_flags(int* __restrict__ flags, int n) {
  int i = blockIdx.x * blockDim.x + threadIdx.x;
  if (i < n) flags[i] = 0;
}

// ------------- per-(b,h) top-7 of M (ties -> smallest index, = lax.top_k) -------------
__global__ __launch_bounds__(256) void topk_kernel(
    const float* __restrict__ Mv, int* __restrict__ idx, int* __restrict__ flags) {
  __shared__ float s[Lc];
  __shared__ float rv[256];
  __shared__ int ri[256];
  const int t = threadIdx.x;
  const int h = blockIdx.x, b = blockIdx.y;
  const float* Mb = Mv + ((size_t)b * Hc + h) * Lc;
  for (int k = t; k < Lc; k += 256) s[k] = Mb[k];
  __syncthreads();
  for (int it = 0; it < Uc; ++it) {
    float bv = -INFINITY;
    int bi = 0x7fffffff;
    for (int k = t; k < Lc; k += 256) {
      float v = s[k];
      if (v > bv || (v == bv && k < bi)) { bv = v; bi = k; }
    }
    rv[t] = bv; ri[t] = bi;
    __syncthreads();
    for (int stride = 128; stride > 0; stride >>= 1) {
      if (t < stride) {
        float ov = rv[t + stride]; int oi = ri[t + stride];
        if (ov > rv[t] || (ov == rv[t] && oi < ri[t])) { rv[t] = ov; ri[t] = oi; }
      }
      __syncthreads();
    }
    if (t == 0) {
      int w = ri[0];
      idx[((size_t)b * Hc + h) * Uc + it] = w;
      flags[b * Lc + w] = 1;
      s[w] = -INFINITY;
    }
    __syncthreads();
  }
}

// ------------- attention for the selected queries -------------
// grid (U, H, B), block 256. ctx[b,h,u,:] = softmax(q_sel.K*scale) @ V
__global__ __launch_bounds__(256) void attn_kernel(
    const float* __restrict__ Q, const float* __restrict__ K,
    const float* __restrict__ V, const int* __restrict__ idx,
    float* __restrict__ ctx) {
  __shared__ float qs[DKc];
  __shared__ float p[Lc];
  __shared__ float red[256];
  const int t = threadIdx.x;
  const int u = blockIdx.x, h = blockIdx.y, b = blockIdx.z;
  const int l = idx[((size_t)b * Hc + h) * Uc + u];
  if (t < DKc) qs[t] = Q[((size_t)b * Lc + l) * Dc + h * DKc + t];
  __syncthreads();
  const float* Kb = K + (size_t)b * Lc * Dc + (size_t)h * DKc;
  float lm = -INFINITY;
  for (int k = t; k < Lc; k += 256) {
    const float* Kr = Kb + (size_t)k * Dc;
    float s = 0.f;
#pragma unroll
    for (int d = 0; d < DKc; d += 4) {
      float4 kv = *(const float4*)(Kr + d);
      float4 qv = *(const float4*)(qs + d);
      s = fmaf(kv.x, qv.x, s); s = fmaf(kv.y, qv.y, s);
      s = fmaf(kv.z, qv.z, s); s = fmaf(kv.w, qv.w, s);
    }
    s *= 0.125f;
    p[k] = s;
    lm = fmaxf(lm, s);
  }
  red[t] = lm;
  __syncthreads();
  for (int st = 128; st > 0; st >>= 1) {
    if (t < st) red[t] = fmaxf(red[t], red[t + st]);
    __syncthreads();
  }
  float m = red[0];
  __syncthreads();
  float ls = 0.f;
  for (int k = t; k < Lc; k += 256) {
    float e = expf(p[k] - m);
    p[k] = e;
    ls += e;
  }
  red[t] = ls;
  __syncthreads();
  for (int st = 128; st > 0; st >>= 1) {
    if (t < st) red[t] += red[t + st];
    __syncthreads();
  }
  float Z = red[0];
  __syncthreads();
  // PV: thread t -> dim d = t&63, quarter of keys = t>>6
  const int d = t & 63, part = t >> 6;
  const float* Vb = V + (size_t)b * Lc * Dc + (size_t)h * DKc + d;
  float a = 0.f;
  for (int k = part * 512; k < part * 512 + 512; ++k)
    a = fmaf(p[k], Vb[(size_t)k * Dc], a);
  red[t] = a;
  __syncthreads();
  if (t < DKc) {
    float v = (red[t] + red[t + 64] + red[t + 128] + red[t + 192]) / Z;
    ctx[(((size_t)b * Hc + h) * Uc + u) * DKc + t] = v;
  }
}

// ------------- sparse output projection -------------
// grid (L, B), block 256. Row l: if unselected -> bo; else gemv over matched heads only.
__global__ __launch_bounds__(256) void output_kernel(
    const float* __restrict__ ctx, const int* __restrict__ idx,
    const int* __restrict__ flags, const float* __restrict__ wo,
    const float* __restrict__ bo, float* __restrict__ out) {
  const int t = threadIdx.x;
  const int l = blockIdx.x, b = blockIdx.y;
  float* orow = out + ((size_t)b * Lc + l) * Dc;
  if (flags[b * Lc + l] == 0) {
#pragma unroll
    for (int j = 0; j < 4; ++j) orow[t + j * 256] = bo[t + j * 256];
    return;
  }
  __shared__ float prow[Dc];
  __shared__ int mh[Hc], mu[Hc];
  __shared__ int nm;
#pragma unroll
  for (int j = 0; j < 4; ++j) prow[t + j * 256] = 0.f;
  if (t == 0) {
    int c = 0;
    for (int h = 0; h < Hc; ++h)
      for (int u = 0; u < Uc; ++u)
        if (idx[(b * Hc + h) * Uc + u] == l) { mh[c] = h; mu[c] = u; ++c; }
    nm = c;
  }
  __syncthreads();
  const int c = nm;
  for (int m = 0; m < c; ++m) {
    if (t < DKc) prow[mh[m] * DKc + t] = ctx[((b * Hc + mh[m]) * Uc + mu[m]) * DKc + t];
  }
  __syncthreads();
  float acc[4] = {0.f, 0.f, 0.f, 0.f};
  for (int m = 0; m < c; ++m) {
    const int dbase = mh[m] * DKc;
    for (int d = 0; d < DKc; d += 4) {
      float4 pv = *(const float4*)(prow + dbase + d);
#pragma unroll
      for (int j = 0; j < 4; ++j) {
        const int n = t + j * 256;
        float4 wv = *(const float4*)(wo + (size_t)n * Dc + dbase + d);
        acc[j] += pv.x * wv.x + pv.y * wv.y + pv.z * wv.z + pv.w * wv.w;
      }
    }
  }
#pragma unroll
  for (int j = 0; j < 4; ++j) {
    const int n = t + j * 256;
    orow[n] = acc[j] + bo[n];
  }
}

extern "C" void kernel_launch(void* const* d_in, const int* in_sizes, int n_in,
                              void* d_out, int out_size, void* d_ws, size_t ws_size,
                              hipStream_t stream) {
  const float* x  = (const float*)d_in[0];
  const float* wq = (const float*)d_in[1];
  const float* bq = (const float*)d_in[2];
  const float* wk = (const float*)d_in[3];
  const float* bk = (const float*)d_in[4];
  const float* wv = (const float*)d_in[5];
  const float* bv = (const float*)d_in[6];
  const float* wo = (const float*)d_in[7];
  const float* bo = (const float*)d_in[8];
  float* out = (float*)d_out;

  char* ws = (char*)d_ws;
  size_t off = 0;
  auto alloc = [&](size_t bytes) -> void* {
    void* p = ws + off;
    off += (bytes + 255) & ~(size_t)255;
    return p;
  };
  float* Q   = (float*)alloc(sizeof(float) * (size_t)Bc * Lc * Dc);   // 33.5 MB
  float* K   = (float*)alloc(sizeof(float) * (size_t)Bc * Lc * Dc);
  float* V   = (float*)alloc(sizeof(float) * (size_t)Bc * Lc * Dc);
  float* Mv  = (float*)alloc(sizeof(float) * (size_t)Bc * Hc * Lc);   // 512 KB
  float* ctx = (float*)alloc(sizeof(float) * (size_t)Bc * Hc * Uc * DKc);
  int*   idx = (int*)alloc(sizeof(int) * (size_t)Bc * Hc * Uc);
  int*   flg = (int*)alloc(sizeof(int) * (size_t)Bc * Lc);

  const dim3 gp(Dc / 128, (Bc * Lc) / 128);  // (8, 64)
  proj_gemm<<<gp, 256, 0, stream>>>(x, wq, bq, Q, Bc * Lc, Dc, Dc);
  proj_gemm<<<gp, 256, 0, stream>>>(x, wk, bk, K, Bc * Lc, Dc, Dc);
  proj_gemm<<<gp, 256, 0, stream>>>(x, wv, bv, V, Bc * Lc, Dc, Dc);
  rowmax_kernel<<<dim3(Lc / 128, Hc, Bc), 256, 0, stream>>>(Q, K, Mv);
  zero_flags<<<dim3((Bc * Lc + 255) / 256), 256, 0, stream>>>(flg, Bc * Lc);
  topk_kernel<<<dim3(Hc, Bc), 256, 0, stream>>>(Mv, idx, flg);
  attn_kernel<<<dim3(Uc, Hc, Bc), 256, 0, stream>>>(Q, K, V, idx, ctx);
  output_kernel<<<dim3(Lc, Bc), 256, 0, stream>>>(ctx, idx, flg, wo, bo, out);
}

// Round 2
// 518.613 us; speedup vs baseline: 2.4641x; 2.4641x over previous
//
#include <hip/hip_runtime.h>
#include <math.h>

// ProbSparse attention (Informer-style). B=4, L=2048, D=1024, H=16, dk=64, u=7.
// Heavy GEMMs run on MFMA via 2-term fp16 split: x = h1 + h2/1024,
// a.b = h1g1 + (h2g1 + h1g2)/1024  (error ~2^-21 per product, fp32-class).
#define Bc 4
#define Lc 2048
#define Dc 1024
#define Hc 16
#define DKc 64
#define Uc 7

typedef _Float16 half8 __attribute__((ext_vector_type(8)));
typedef _Float16 half4 __attribute__((ext_vector_type(4)));
typedef float f32x4 __attribute__((ext_vector_type(4)));

#define MFMA16(a, b, c) __builtin_amdgcn_mfma_f32_16x16x32_f16(a, b, c, 0, 0, 0)

#define GLOAD16(gsrc, ldst)                                                    \
  __builtin_amdgcn_global_load_lds(                                            \
      (const __attribute__((address_space(1))) void*)(gsrc),                   \
      (__attribute__((address_space(3))) void*)(ldst), 16, 0, 0)

// Stage a [128 rows][64 fp16] tile (row stride ld elems) into LDS, linear dest,
// XOR-swizzled global source: LDS slot s holds global chunk (s&7)^((s>>3)&7).
__device__ __forceinline__ void stage_tile(const _Float16* __restrict__ g, int ld,
                                           _Float16* lds, int t) {
#pragma unroll
  for (int j = 0; j < 4; ++j) {
    int s = t + j * 256;                 // slot 0..1023
    int r = s >> 3;                      // row 0..127
    int c = (s & 7) ^ (r & 7);           // swizzled source chunk
    GLOAD16(g + (size_t)r * ld + c * 8, lds + (size_t)s * 8);
  }
}

// Read an 8-fp16 MFMA fragment from a swizzled [*][64] tile.
__device__ __forceinline__ half8 read_frag(const _Float16* lds, int row, int g) {
  int chunk = g ^ (row & 7);
  return *(const half8*)(lds + (size_t)row * 64 + chunk * 8);
}

// ---------------- split kernels ----------------
__global__ void split_plain(const float* __restrict__ src, _Float16* __restrict__ d1,
                            _Float16* __restrict__ d2, int n) {
  int i = (blockIdx.x * 256 + threadIdx.x) * 4;
  if (i >= n) return;
  float4 v = *(const float4*)(src + i);
  float vv[4] = {v.x, v.y, v.z, v.w};
  half4 o1, o2;
#pragma unroll
  for (int j = 0; j < 4; ++j) {
    _Float16 h1 = (_Float16)vv[j];
    o1[j] = h1;
    o2[j] = (_Float16)((vv[j] - (float)h1) * 1024.0f);
  }
  *(half4*)(d1 + i) = o1;
  *(half4*)(d2 + i) = o2;
}

// src fp32 [B,L,H,64] -> per-head layout [B*H, L, 64] fp16 splits
__global__ void split_head(const float* __restrict__ src, _Float16* __restrict__ d1,
                           _Float16* __restrict__ d2) {
  int o = (blockIdx.x * 256 + threadIdx.x) * 4;
  int d = o & 63;
  int rest = o >> 6;          // bh*L + l
  int lidx = rest & (Lc - 1);
  int bh = rest >> 11;
  int b = bh >> 4, h = bh & 15;
  const float* s = src + ((size_t)(b * Lc + lidx) * Dc) + h * DKc + d;
  float4 v = *(const float4*)s;
  float vv[4] = {v.x, v.y, v.z, v.w};
  half4 o1, o2;
#pragma unroll
  for (int j = 0; j < 4; ++j) {
    _Float16 h1 = (_Float16)vv[j];
    o1[j] = h1;
    o2[j] = (_Float16)((vv[j] - (float)h1) * 1024.0f);
  }
  *(half4*)(d1 + o) = o1;
  *(half4*)(d2 + o) = o2;
}

// ---------------- split-fp16 MFMA projection GEMM ----------------
// C[M,N] = A[M,K] @ W[N,K]^T + bias, A/W given as (h1, h2*1024) fp16 pairs.
// grid (M/128, N/128), block 256 (4 waves, 2x2), 128x128 tile, BK=64.
__global__ __launch_bounds__(256, 2) void proj_mfma(
    const _Float16* __restrict__ A1, const _Float16* __restrict__ A2,
    const _Float16* __restrict__ W1, const _Float16* __restrict__ W2,
    const float* __restrict__ bias, float* __restrict__ C, int M, int N, int K) {
  __shared__ __align__(16) _Float16 sA1[128 * 64];
  __shared__ __align__(16) _Float16 sA2[128 * 64];
  __shared__ __align__(16) _Float16 sW1[128 * 64];
  __shared__ __align__(16) _Float16 sW2[128 * 64];
  const int t = threadIdx.x;
  const int l = t & 63;
  const int wid = t >> 6;
  const int wm = wid >> 1, wn = wid & 1;
  const int bm = blockIdx.x * 128;   // x = m-tile so same-m blocks share an XCD
  const int bn = blockIdx.y * 128;
  f32x4 hi[4][4] = {};
  f32x4 lo[4][4] = {};
  for (int k0 = 0; k0 < K; k0 += 64) {
    __syncthreads();
    stage_tile(A1 + (size_t)bm * K + k0, K, sA1, t);
    stage_tile(A2 + (size_t)bm * K + k0, K, sA2, t);
    stage_tile(W1 + (size_t)bn * K + k0, K, sW1, t);
    stage_tile(W2 + (size_t)bn * K + k0, K, sW2, t);
    __syncthreads();
#pragma unroll
    for (int ks = 0; ks < 2; ++ks) {
      const int g = ks * 4 + (l >> 4);
      half8 a1[4], a2[4], b1[4], b2[4];
#pragma unroll
      for (int i = 0; i < 4; ++i) {
        int ra = wm * 64 + i * 16 + (l & 15);
        a1[i] = read_frag(sA1, ra, g);
        a2[i] = read_frag(sA2, ra, g);
        int rb = wn * 64 + i * 16 + (l & 15);
        b1[i] = read_frag(sW1, rb, g);
        b2[i] = read_frag(sW2, rb, g);
      }
#pragma unroll
      for (int i = 0; i < 4; ++i)
#pragma unroll
        for (int j = 0; j < 4; ++j) {
          hi[i][j] = MFMA16(a1[i], b1[j], hi[i][j]);
          lo[i][j] = MFMA16(a2[i], b1[j], lo[i][j]);
          lo[i][j] = MFMA16(a1[i], b2[j], lo[i][j]);
        }
    }
  }
#pragma unroll
  for (int i = 0; i < 4; ++i) {
    int m = bm + wm * 64 + i * 16 + ((l >> 4) << 2);
#pragma unroll
    for (int j = 0; j < 4; ++j) {
      int n = bn + wn * 64 + j * 16 + (l & 15);
      float bv = bias[n];
#pragma unroll
      for (int r = 0; r < 4; ++r)
        C[(size_t)(m + r) * N + n] = hi[i][j][r] + lo[i][j][r] * (1.0f / 1024.0f) + bv;
    }
  }
}

// ---------------- MFMA row-max of QK^T (never materializes S) ----------------
// grid (BH=64, L/128=16), block 256. Q1/Q2/K1/K2: [BH][L][64] fp16.
__global__ __launch_bounds__(256, 2) void rowmax_mfma(
    const _Float16* __restrict__ Q1, const _Float16* __restrict__ Q2,
    const _Float16* __restrict__ K1, const _Float16* __restrict__ K2,
    float* __restrict__ Mout) {
  __shared__ __align__(16) _Float16 sQ1[128 * 64];
  __shared__ __align__(16) _Float16 sQ2[128 * 64];
  __shared__ __align__(16) _Float16 sK1[128 * 64];
  __shared__ __align__(16) _Float16 sK2[128 * 64];
  __shared__ float Red[2][128];
  const int t = threadIdx.x;
  const int l = t & 63;
  const int wid = t >> 6;
  const int wm = wid >> 1, wn = wid & 1;
  const int bh = blockIdx.x;       // x = bh so each bh's K panel stays in one XCD L2
  const int q0 = blockIdx.y * 128;
  const _Float16* Q1b = Q1 + ((size_t)bh * Lc + q0) * DKc;
  const _Float16* Q2b = Q2 + ((size_t)bh * Lc + q0) * DKc;
  const _Float16* K1b = K1 + (size_t)bh * Lc * DKc;
  const _Float16* K2b = K2 + (size_t)bh * Lc * DKc;
  stage_tile(Q1b, 64, sQ1, t);
  stage_tile(Q2b, 64, sQ2, t);
  float rm[4][4];
#pragma unroll
  for (int i = 0; i < 4; ++i)
#pragma unroll
    for (int r = 0; r < 4; ++r) rm[i][r] = -INFINITY;
  for (int kt = 0; kt < Lc / 128; ++kt) {
    __syncthreads();
    stage_tile(K1b + (size_t)kt * 128 * 64, 64, sK1, t);
    stage_tile(K2b + (size_t)kt * 128 * 64, 64, sK2, t);
    __syncthreads();
    f32x4 hi[4][4] = {};
    f32x4 lo[4][4] = {};
#pragma unroll
    for (int ks = 0; ks < 2; ++ks) {
      const int g = ks * 4 + (l >> 4);
      half8 a1[4], a2[4], b1[4], b2[4];
#pragma unroll
      for (int i = 0; i < 4; ++i) {
        int ra = wm * 64 + i * 16 + (l & 15);
        a1[i] = read_frag(sQ1, ra, g);
        a2[i] = read_frag(sQ2, ra, g);
        int rb = wn * 64 + i * 16 + (l & 15);
        b1[i] = read_frag(sK1, rb, g);
        b2[i] = read_frag(sK2, rb, g);
      }
#pragma unroll
      for (int i = 0; i < 4; ++i)
#pragma unroll
        for (int j = 0; j < 4; ++j) {
          hi[i][j] = MFMA16(a1[i], b1[j], hi[i][j]);
          lo[i][j] = MFMA16(a2[i], b1[j], lo[i][j]);
          lo[i][j] = MFMA16(a1[i], b2[j], lo[i][j]);
        }
    }
#pragma unroll
    for (int i = 0; i < 4; ++i)
#pragma unroll
      for (int j = 0; j < 4; ++j)
#pragma unroll
        for (int r = 0; r < 4; ++r) {
          float s = hi[i][j][r] + lo[i][j][r] * (1.0f / 1024.0f);
          rm[i][r] = fmaxf(rm[i][r], s);
        }
  }
  // max across the 16 lanes holding the same output rows (cols of the tile)
#pragma unroll
  for (int i = 0; i < 4; ++i)
#pragma unroll
    for (int r = 0; r < 4; ++r) {
      float v = rm[i][r];
#pragma unroll
      for (int off = 1; off < 16; off <<= 1) v = fmaxf(v, __shfl_xor(v, off, 64));
      rm[i][r] = v;
    }
  if ((l & 15) == 0) {
#pragma unroll
    for (int i = 0; i < 4; ++i)
#pragma unroll
      for (int r = 0; r < 4; ++r)
        Red[wn][wm * 64 + i * 16 + ((l >> 4) << 2) + r] = rm[i][r];
  }
  __syncthreads();
  if (t < 128)
    Mout[(size_t)bh * Lc + q0 + t] = 0.125f * fmaxf(Red[0][t], Red[1][t]);
}

__global__ void zero_flags(int* __restrict__ flags, int n) {
  int i = blockIdx.x * blockDim.x + threadIdx.x;
  if (i < n) flags[i] = 0;
}

// ------------- per-(b,h) top-7 of M (ties -> smallest index) -------------
__global__ __launch_bounds__(256) void topk_kernel(
    const float* __restrict__ Mv, int* __restrict__ idx, int* __restrict__ flags) {
  __shared__ float s[Lc];
  __shared__ float rv[256];
  __shared__ int ri[256];
  const int t = threadIdx.x;
  const int h = blockIdx.x, b = blockIdx.y;
  const float* Mb = Mv + ((size_t)b * Hc + h) * Lc;
  for (int k = t; k < Lc; k += 256) s[k] = Mb[k];
  __syncthreads();
  for (int it = 0; it < Uc; ++it) {
    float bv = -INFINITY;
    int bi = 0x7fffffff;
    for (int k = t; k < Lc; k += 256) {
      float v = s[k];
      if (v > bv || (v == bv && k < bi)) { bv = v; bi = k; }
    }
    rv[t] = bv; ri[t] = bi;
    __syncthreads();
    for (int stride = 128; stride > 0; stride >>= 1) {
      if (t < stride) {
        float ov = rv[t + stride]; int oi = ri[t + stride];
        if (ov > rv[t] || (ov == rv[t] && oi < ri[t])) { rv[t] = ov; ri[t] = oi; }
      }
      __syncthreads();
    }
    if (t == 0) {
      int w = ri[0];
      idx[((size_t)b * Hc + h) * Uc + it] = w;
      flags[b * Lc + w] = 1;
      s[w] = -INFINITY;
    }
    __syncthreads();
  }
}

// ------------- attention for the selected queries (fp32) -------------
__global__ __launch_bounds__(256) void attn_kernel(
    const float* __restrict__ Q, const float* __restrict__ K,
    const float* __restrict__ V, const int* __restrict__ idx,
    float* __restrict__ ctx) {
  __shared__ float qs[DKc];
  __shared__ float p[Lc];
  __shared__ float red[256];
  const int t = threadIdx.x;
  const int u = blockIdx.x, h = blockIdx.y, b = blockIdx.z;
  const int l = idx[((size_t)b * Hc + h) * Uc + u];
  if (t < DKc) qs[t] = Q[((size_t)b * Lc + l) * Dc + h * DKc + t];
  __syncthreads();
  const float* Kb = K + (size_t)b * Lc * Dc + (size_t)h * DKc;
  float lm = -INFINITY;
  for (int k = t; k < Lc; k += 256) {
    const float* Kr = Kb + (size_t)k * Dc;
    float s = 0.f;
#pragma unroll
    for (int d = 0; d < DKc; d += 4) {
      float4 kv = *(const float4*)(Kr + d);
      float4 qv = *(const float4*)(qs + d);
      s = fmaf(kv.x, qv.x, s); s = fmaf(kv.y, qv.y, s);
      s = fmaf(kv.z, qv.z, s); s = fmaf(kv.w, qv.w, s);
    }
    s *= 0.125f;
    p[k] = s;
    lm = fmaxf(lm, s);
  }
  red[t] = lm;
  __syncthreads();
  for (int st = 128; st > 0; st >>= 1) {
    if (t < st) red[t] = fmaxf(red[t], red[t + st]);
    __syncthreads();
  }
  float m = red[0];
  __syncthreads();
  float ls = 0.f;
  for (int k = t; k < Lc; k += 256) {
    float e = expf(p[k] - m);
    p[k] = e;
    ls += e;
  }
  red[t] = ls;
  __syncthreads();
  for (int st = 128; st > 0; st >>= 1) {
    if (t < st) red[t] += red[t + st];
    __syncthreads();
  }
  float Z = red[0];
  __syncthreads();
  const int d = t & 63, part = t >> 6;
  const float* Vb = V + (size_t)b * Lc * Dc + (size_t)h * DKc + d;
  float a = 0.f;
  for (int k = part * 512; k < part * 512 + 512; ++k)
    a = fmaf(p[k], Vb[(size_t)k * Dc], a);
  red[t] = a;
  __syncthreads();
  if (t < DKc) {
    float v = (red[t] + red[t + 64] + red[t + 128] + red[t + 192]) / Z;
    ctx[(((size_t)b * Hc + h) * Uc + u) * DKc + t] = v;
  }
}

// ------------- sparse output projection -------------
__global__ __launch_bounds__(256) void output_kernel(
    const float* __restrict__ ctx, const int* __restrict__ idx,
    const int* __restrict__ flags, const float* __restrict__ wo,
    const float* __restrict__ bo, float* __restrict__ out) {
  const int t = threadIdx.x;
  const int l = blockIdx.x, b = blockIdx.y;
  float* orow = out + ((size_t)b * Lc + l) * Dc;
  if (flags[b * Lc + l] == 0) {
#pragma unroll
    for (int j = 0; j < 4; ++j) orow[t + j * 256] = bo[t + j * 256];
    return;
  }
  __shared__ float prow[Dc];
  __shared__ int mh[Hc], mu[Hc];
  __shared__ int nm;
#pragma unroll
  for (int j = 0; j < 4; ++j) prow[t + j * 256] = 0.f;
  if (t == 0) {
    int c = 0;
    for (int h = 0; h < Hc; ++h)
      for (int u = 0; u < Uc; ++u)
        if (idx[(b * Hc + h) * Uc + u] == l) { mh[c] = h; mu[c] = u; ++c; }
    nm = c;
  }
  __syncthreads();
  const int c = nm;
  for (int m = 0; m < c; ++m) {
    if (t < DKc) prow[mh[m] * DKc + t] = ctx[((b * Hc + mh[m]) * Uc + mu[m]) * DKc + t];
  }
  __syncthreads();
  float acc[4] = {0.f, 0.f, 0.f, 0.f};
  for (int m = 0; m < c; ++m) {
    const int dbase = mh[m] * DKc;
    for (int d = 0; d < DKc; d += 4) {
      float4 pv = *(const float4*)(prow + dbase + d);
#pragma unroll
      for (int j = 0; j < 4; ++j) {
        const int n = t + j * 256;
        float4 wv = *(const float4*)(wo + (size_t)n * Dc + dbase + d);
        acc[j] += pv.x * wv.x + pv.y * wv.y + pv.z * wv.z + pv.w * wv.w;
      }
    }
  }
#pragma unroll
  for (int j = 0; j < 4; ++j) {
    const int n = t + j * 256;
    orow[n] = acc[j] + bo[n];
  }
}

extern "C" void kernel_launch(void* const* d_in, const int* in_sizes, int n_in,
                              void* d_out, int out_size, void* d_ws, size_t ws_size,
                              hipStream_t stream) {
  const float* x  = (const float*)d_in[0];
  const float* wq = (const float*)d_in[1];
  const float* bq = (const float*)d_in[2];
  const float* wk = (const float*)d_in[3];
  const float* bk = (const float*)d_in[4];
  const float* wv = (const float*)d_in[5];
  const float* bv = (const float*)d_in[6];
  const float* wo = (const float*)d_in[7];
  const float* bo = (const float*)d_in[8];
  float* out = (float*)d_out;

  char* ws = (char*)d_ws;
  size_t off = 0;
  auto alloc = [&](size_t bytes) -> void* {
    void* p = ws + off;
    off += (bytes + 255) & ~(size_t)255;
    return p;
  };
  const size_t NE = (size_t)Bc * Lc * Dc;           // 8388608
  float* Q   = (float*)alloc(sizeof(float) * NE);
  float* K   = (float*)alloc(sizeof(float) * NE);
  float* V   = (float*)alloc(sizeof(float) * NE);
  float* Mv  = (float*)alloc(sizeof(float) * (size_t)Bc * Hc * Lc);
  float* ctx = (float*)alloc(sizeof(float) * (size_t)Bc * Hc * Uc * DKc);
  int*   idx = (int*)alloc(sizeof(int) * (size_t)Bc * Hc * Uc);
  int*   flg = (int*)alloc(sizeof(int) * (size_t)Bc * Lc);
  _Float16* x1 = (_Float16*)alloc(2 * NE);          // reused as Q1h after projs
  _Float16* x2 = (_Float16*)alloc(2 * NE);          // reused as Q2h after projs
  _Float16* w1 = (_Float16*)alloc(2 * (size_t)Dc * Dc);
  _Float16* w2 = (_Float16*)alloc(2 * (size_t)Dc * Dc);
  _Float16* k1h = (_Float16*)alloc(2 * NE);
  _Float16* k2h = (_Float16*)alloc(2 * NE);

  const int M = Bc * Lc;                            // 8192
  // splits of x and weights
  split_plain<<<dim3(NE / 1024), 256, 0, stream>>>(x, x1, x2, (int)NE);
  const dim3 gp(M / 128, Dc / 128);                 // (64, 8)

  split_plain<<<dim3(Dc * Dc / 1024), 256, 0, stream>>>(wq, w1, w2, Dc * Dc);
  proj_mfma<<<gp, 256, 0, stream>>>(x1, x2, w1, w2, bq, Q, M, Dc, Dc);
  split_plain<<<dim3(Dc * Dc / 1024), 256, 0, stream>>>(wk, w1, w2, Dc * Dc);
  proj_mfma<<<gp, 256, 0, stream>>>(x1, x2, w1, w2, bk, K, M, Dc, Dc);
  split_plain<<<dim3(Dc * Dc / 1024), 256, 0, stream>>>(wv, w1, w2, Dc * Dc);
  proj_mfma<<<gp, 256, 0, stream>>>(x1, x2, w1, w2, bv, V, M, Dc, Dc);

  // per-head fp16 splits of Q, K (x1/x2 are dead now -> reuse as Q splits)
  _Float16* q1h = x1;
  _Float16* q2h = x2;
  split_head<<<dim3(NE / 1024), 256, 0, stream>>>(Q, q1h, q2h);
  split_head<<<dim3(NE / 1024), 256, 0, stream>>>(K, k1h, k2h);

  rowmax_mfma<<<dim3(Bc * Hc, Lc / 128), 256, 0, stream>>>(q1h, q2h, k1h, k2h, Mv);

  zero_flags<<<dim3((Bc * Lc + 255) / 256), 256, 0, stream>>>(flg, Bc * Lc);
  topk_kernel<<<dim3(Hc, Bc), 256, 0, stream>>>(Mv, idx, flg);
  attn_kernel<<<dim3(Uc, Hc, Bc), 256, 0, stream>>>(Q, K, V, idx, ctx);
  output_kernel<<<dim3(Lc, Bc), 256, 0, stream>>>(ctx, idx, flg, wo, bo, out);
}

// Round 3
// 355.308 us; speedup vs baseline: 3.5966x; 1.4596x over previous
//
#include <hip/hip_runtime.h>
#include <math.h>

// ProbSparse attention (Informer-style). B=4, L=2048, D=1024, H=16, dk=64, u=7.
// Heavy GEMMs run on MFMA via 2-term fp16 split: x = h1 + h2/1024,
// a.b = h1g1 + (h2g1 + h1g2)/1024  (error ~2^-21 per product, fp32-class).
#define Bc 4
#define Lc 2048
#define Dc 1024
#define Hc 16
#define DKc 64
#define Uc 7
#define KPc 8          // key-split parts in attention
#define KPNc (Lc / KPc)

typedef _Float16 half8 __attribute__((ext_vector_type(8)));
typedef _Float16 half4 __attribute__((ext_vector_type(4)));
typedef float f32x4 __attribute__((ext_vector_type(4)));

#define MFMA16(a, b, c) __builtin_amdgcn_mfma_f32_16x16x32_f16(a, b, c, 0, 0, 0)

#define GLOAD16(gsrc, ldst)                                                    \
  __builtin_amdgcn_global_load_lds(                                            \
      (const __attribute__((address_space(1))) void*)(gsrc),                   \
      (__attribute__((address_space(3))) void*)(ldst), 16, 0, 0)

// Stage a [128 rows][64 fp16] tile (row stride ld elems) into LDS, linear dest,
// XOR-swizzled global source: LDS slot s holds global chunk (s&7)^((s>>3)&7).
__device__ __forceinline__ void stage_tile(const _Float16* __restrict__ g, int ld,
                                           _Float16* lds, int t) {
#pragma unroll
  for (int j = 0; j < 4; ++j) {
    int s = t + j * 256;                 // slot 0..1023
    int r = s >> 3;                      // row 0..127
    int c = (s & 7) ^ (r & 7);           // swizzled source chunk
    GLOAD16(g + (size_t)r * ld + c * 8, lds + (size_t)s * 8);
  }
}

// Read an 8-fp16 MFMA fragment from a swizzled [*][64] tile.
__device__ __forceinline__ half8 read_frag(const _Float16* lds, int row, int g) {
  int chunk = g ^ (row & 7);
  return *(const half8*)(lds + (size_t)row * 64 + chunk * 8);
}

// ---------------- split kernel (fp32 -> fp16 pair) ----------------
__global__ void split_plain(const float* __restrict__ src, _Float16* __restrict__ d1,
                            _Float16* __restrict__ d2, int n) {
  int i = (blockIdx.x * 256 + threadIdx.x) * 4;
  if (i >= n) return;
  float4 v = *(const float4*)(src + i);
  float vv[4] = {v.x, v.y, v.z, v.w};
  half4 o1, o2;
#pragma unroll
  for (int j = 0; j < 4; ++j) {
    _Float16 h1 = (_Float16)vv[j];
    o1[j] = h1;
    o2[j] = (_Float16)((vv[j] - (float)h1) * 1024.0f);
  }
  *(half4*)(d1 + i) = o1;
  *(half4*)(d2 + i) = o2;
}

// ---------------- split-fp16 MFMA projection GEMM ----------------
// C[M,N] = A[M,K] @ W[N,K]^T + bias, A/W given as (h1, h2*1024) fp16 pairs.
// MODE 0: write fp32 C [M][N].
// MODE 1: write per-head fp16 split pair d1/d2 at [B*H][L][64] (no fp32 C).
// grid (M/128, N/128), block 256 (4 waves, 2x2), 128x128 tile, BK=64.
template <int MODE>
__global__ __launch_bounds__(256, 2) void proj_mfma(
    const _Float16* __restrict__ A1, const _Float16* __restrict__ A2,
    const _Float16* __restrict__ W1, const _Float16* __restrict__ W2,
    const float* __restrict__ bias, float* __restrict__ C,
    _Float16* __restrict__ d1, _Float16* __restrict__ d2, int M, int N, int K) {
  __shared__ __align__(16) _Float16 sA1[128 * 64];
  __shared__ __align__(16) _Float16 sA2[128 * 64];
  __shared__ __align__(16) _Float16 sW1[128 * 64];
  __shared__ __align__(16) _Float16 sW2[128 * 64];
  const int t = threadIdx.x;
  const int l = t & 63;
  const int wid = t >> 6;
  const int wm = wid >> 1, wn = wid & 1;
  const int bm = blockIdx.x * 128;
  const int bn = blockIdx.y * 128;
  f32x4 hi[4][4] = {};
  f32x4 lo[4][4] = {};
  for (int k0 = 0; k0 < K; k0 += 64) {
    __syncthreads();
    stage_tile(A1 + (size_t)bm * K + k0, K, sA1, t);
    stage_tile(A2 + (size_t)bm * K + k0, K, sA2, t);
    stage_tile(W1 + (size_t)bn * K + k0, K, sW1, t);
    stage_tile(W2 + (size_t)bn * K + k0, K, sW2, t);
    __syncthreads();
#pragma unroll
    for (int ks = 0; ks < 2; ++ks) {
      const int g = ks * 4 + (l >> 4);
      half8 a1[4], a2[4], b1[4], b2[4];
#pragma unroll
      for (int i = 0; i < 4; ++i) {
        int ra = wm * 64 + i * 16 + (l & 15);
        a1[i] = read_frag(sA1, ra, g);
        a2[i] = read_frag(sA2, ra, g);
        int rb = wn * 64 + i * 16 + (l & 15);
        b1[i] = read_frag(sW1, rb, g);
        b2[i] = read_frag(sW2, rb, g);
      }
#pragma unroll
      for (int i = 0; i < 4; ++i)
#pragma unroll
        for (int j = 0; j < 4; ++j) {
          hi[i][j] = MFMA16(a1[i], b1[j], hi[i][j]);
          lo[i][j] = MFMA16(a2[i], b1[j], lo[i][j]);
          lo[i][j] = MFMA16(a1[i], b2[j], lo[i][j]);
        }
    }
  }
#pragma unroll
  for (int i = 0; i < 4; ++i) {
    int m = bm + wm * 64 + i * 16 + ((l >> 4) << 2);
#pragma unroll
    for (int j = 0; j < 4; ++j) {
      int n = bn + wn * 64 + j * 16 + (l & 15);
      float bv = bias[n];
#pragma unroll
      for (int r = 0; r < 4; ++r) {
        float val = hi[i][j][r] + lo[i][j][r] * (1.0f / 1024.0f) + bv;
        if (MODE == 0) {
          C[(size_t)(m + r) * N + n] = val;
        } else {
          int head = n >> 6, d = n & 63;
          int mm = m + r;
          int bb = mm >> 11, ltok = mm & (Lc - 1);
          size_t o = ((size_t)(bb * Hc + head) * Lc + ltok) * DKc + d;
          _Float16 h1 = (_Float16)val;
          d1[o] = h1;
          d2[o] = (_Float16)((val - (float)h1) * 1024.0f);
        }
      }
    }
  }
}

// ---------------- MFMA row-max of QK^T (never materializes S) ----------------
// grid (BH=64, L/128=16), block 256. Q1/Q2/K1/K2: [BH][L][64] fp16.
__global__ __launch_bounds__(256, 2) void rowmax_mfma(
    const _Float16* __restrict__ Q1, const _Float16* __restrict__ Q2,
    const _Float16* __restrict__ K1, const _Float16* __restrict__ K2,
    float* __restrict__ Mout) {
  __shared__ __align__(16) _Float16 sQ1[128 * 64];
  __shared__ __align__(16) _Float16 sQ2[128 * 64];
  __shared__ __align__(16) _Float16 sK1[128 * 64];
  __shared__ __align__(16) _Float16 sK2[128 * 64];
  __shared__ float Red[2][128];
  const int t = threadIdx.x;
  const int l = t & 63;
  const int wid = t >> 6;
  const int wm = wid >> 1, wn = wid & 1;
  const int bh = blockIdx.x;
  const int q0 = blockIdx.y * 128;
  const _Float16* Q1b = Q1 + ((size_t)bh * Lc + q0) * DKc;
  const _Float16* Q2b = Q2 + ((size_t)bh * Lc + q0) * DKc;
  const _Float16* K1b = K1 + (size_t)bh * Lc * DKc;
  const _Float16* K2b = K2 + (size_t)bh * Lc * DKc;
  stage_tile(Q1b, 64, sQ1, t);
  stage_tile(Q2b, 64, sQ2, t);
  float rm[4][4];
#pragma unroll
  for (int i = 0; i < 4; ++i)
#pragma unroll
    for (int r = 0; r < 4; ++r) rm[i][r] = -INFINITY;
  for (int kt = 0; kt < Lc / 128; ++kt) {
    __syncthreads();
    stage_tile(K1b + (size_t)kt * 128 * 64, 64, sK1, t);
    stage_tile(K2b + (size_t)kt * 128 * 64, 64, sK2, t);
    __syncthreads();
    f32x4 hi[4][4] = {};
    f32x4 lo[4][4] = {};
#pragma unroll
    for (int ks = 0; ks < 2; ++ks) {
      const int g = ks * 4 + (l >> 4);
      half8 a1[4], a2[4], b1[4], b2[4];
#pragma unroll
      for (int i = 0; i < 4; ++i) {
        int ra = wm * 64 + i * 16 + (l & 15);
        a1[i] = read_frag(sQ1, ra, g);
        a2[i] = read_frag(sQ2, ra, g);
        int rb = wn * 64 + i * 16 + (l & 15);
        b1[i] = read_frag(sK1, rb, g);
        b2[i] = read_frag(sK2, rb, g);
      }
#pragma unroll
      for (int i = 0; i < 4; ++i)
#pragma unroll
        for (int j = 0; j < 4; ++j) {
          hi[i][j] = MFMA16(a1[i], b1[j], hi[i][j]);
          lo[i][j] = MFMA16(a2[i], b1[j], lo[i][j]);
          lo[i][j] = MFMA16(a1[i], b2[j], lo[i][j]);
        }
    }
#pragma unroll
    for (int i = 0; i < 4; ++i)
#pragma unroll
      for (int j = 0; j < 4; ++j)
#pragma unroll
        for (int r = 0; r < 4; ++r) {
          float s = hi[i][j][r] + lo[i][j][r] * (1.0f / 1024.0f);
          rm[i][r] = fmaxf(rm[i][r], s);
        }
  }
#pragma unroll
  for (int i = 0; i < 4; ++i)
#pragma unroll
    for (int r = 0; r < 4; ++r) {
      float v = rm[i][r];
#pragma unroll
      for (int off = 1; off < 16; off <<= 1) v = fmaxf(v, __shfl_xor(v, off, 64));
      rm[i][r] = v;
    }
  if ((l & 15) == 0) {
#pragma unroll
    for (int i = 0; i < 4; ++i)
#pragma unroll
      for (int r = 0; r < 4; ++r)
        Red[wn][wm * 64 + i * 16 + ((l >> 4) << 2) + r] = rm[i][r];
  }
  __syncthreads();
  if (t < 128)
    Mout[(size_t)bh * Lc + q0 + t] = 0.125f * fmaxf(Red[0][t], Red[1][t]);
}

__global__ void zero_flags(int* __restrict__ flags, int n) {
  int i = blockIdx.x * blockDim.x + threadIdx.x;
  if (i < n) flags[i] = 0;
}

// ------------- per-(b,h) top-7 of M (ties -> smallest index) -------------
__global__ __launch_bounds__(256) void topk_kernel(
    const float* __restrict__ Mv, int* __restrict__ idx, int* __restrict__ flags) {
  __shared__ float s[Lc];
  __shared__ float rv[256];
  __shared__ int ri[256];
  const int t = threadIdx.x;
  const int h = blockIdx.x, b = blockIdx.y;
  const float* Mb = Mv + ((size_t)b * Hc + h) * Lc;
  for (int k = t; k < Lc; k += 256) s[k] = Mb[k];
  __syncthreads();
  for (int it = 0; it < Uc; ++it) {
    float bv = -INFINITY;
    int bi = 0x7fffffff;
    for (int k = t; k < Lc; k += 256) {
      float v = s[k];
      if (v > bv || (v == bv && k < bi)) { bv = v; bi = k; }
    }
    rv[t] = bv; ri[t] = bi;
    __syncthreads();
    for (int stride = 128; stride > 0; stride >>= 1) {
      if (t < stride) {
        float ov = rv[t + stride]; int oi = ri[t + stride];
        if (ov > rv[t] || (ov == rv[t] && oi < ri[t])) { rv[t] = ov; ri[t] = oi; }
      }
      __syncthreads();
    }
    if (t == 0) {
      int w = ri[0];
      idx[((size_t)b * Hc + h) * Uc + it] = w;
      flags[b * Lc + w] = 1;
      s[w] = -INFINITY;
    }
    __syncthreads();
  }
}

// ------------- attention partials: all 7 queries x one key-slice -------------
// grid (KP, H, B), block 256. K from fp16 splits, V fp32.
__global__ __launch_bounds__(256) void attn_part(
    const _Float16* __restrict__ q1, const _Float16* __restrict__ q2,
    const _Float16* __restrict__ k1, const _Float16* __restrict__ k2,
    const float* __restrict__ V, const int* __restrict__ idx,
    float* __restrict__ Pm, float* __restrict__ Pl, float* __restrict__ Pctx) {
  __shared__ float qs[Uc][DKc];
  __shared__ float ps[Uc][KPNc];
  __shared__ float red[4][Uc][DKc];
  __shared__ float mred[Uc], lred[Uc];
  const int t = threadIdx.x;
  const int kp = blockIdx.x, h = blockIdx.y, b = blockIdx.z;
  const int bh = b * Hc + h;
  const int k0 = kp * KPNc;
  // load the 7 selected q rows (reconstructed fp32)
  for (int i = t; i < Uc * DKc; i += 256) {
    int u = i >> 6, d = i & 63;
    int lq = idx[bh * Uc + u];
    size_t o = ((size_t)bh * Lc + lq) * DKc + d;
    qs[u][d] = (float)q1[o] + (float)q2[o] * (1.0f / 1024.0f);
  }
  __syncthreads();
  // scores: thread t owns key k0+t
  const size_t krow = ((size_t)bh * Lc + k0 + t) * DKc;
  float s[Uc] = {};
#pragma unroll
  for (int c = 0; c < 8; ++c) {
    half8 a = *(const half8*)(k1 + krow + c * 8);
    half8 e = *(const half8*)(k2 + krow + c * 8);
    float kv[8];
#pragma unroll
    for (int j = 0; j < 8; ++j) kv[j] = (float)a[j] + (float)e[j] * (1.0f / 1024.0f);
#pragma unroll
    for (int u = 0; u < Uc; ++u)
#pragma unroll
      for (int j = 0; j < 8; ++j) s[u] = fmaf(kv[j], qs[u][c * 8 + j], s[u]);
  }
#pragma unroll
  for (int u = 0; u < Uc; ++u) ps[u][t] = s[u] * 0.125f;
  __syncthreads();
  // per-u max and sum of exp (wave w handles u = w, w+4)
  const int w = t >> 6, lane = t & 63;
  for (int u = w; u < Uc; u += 4) {
    float m = -INFINITY;
    for (int k = lane; k < KPNc; k += 64) m = fmaxf(m, ps[u][k]);
#pragma unroll
    for (int off = 1; off < 64; off <<= 1) m = fmaxf(m, __shfl_xor(m, off, 64));
    float lsum = 0.f;
    for (int k = lane; k < KPNc; k += 64) {
      float e = expf(ps[u][k] - m);
      ps[u][k] = e;
      lsum += e;
    }
#pragma unroll
    for (int off = 1; off < 64; off <<= 1) lsum += __shfl_xor(lsum, off, 64);
    if (lane == 0) { mred[u] = m; lred[u] = lsum; }
  }
  __syncthreads();
  // PV: wave g handles keys [g*64, g*64+64), thread dim d = lane
  const int d = lane, g = w;
  float acc[Uc] = {};
  const float* Vb = V + (size_t)b * Lc * Dc + (size_t)h * DKc + d;
  for (int kk = g * (KPNc / 4); kk < (g + 1) * (KPNc / 4); ++kk) {
    float v = Vb[(size_t)(k0 + kk) * Dc];
#pragma unroll
    for (int u = 0; u < Uc; ++u) acc[u] = fmaf(ps[u][kk], v, acc[u]);
  }
#pragma unroll
  for (int u = 0; u < Uc; ++u) red[g][u][d] = acc[u];
  __syncthreads();
  for (int i = t; i < Uc * DKc; i += 256) {
    int u = i >> 6, dd = i & 63;
    float v = red[0][u][dd] + red[1][u][dd] + red[2][u][dd] + red[3][u][dd];
    Pctx[((size_t)(bh * Uc + u) * KPc + kp) * DKc + dd] = v;
  }
  if (t < Uc) {
    Pm[(bh * Uc + t) * KPc + kp] = mred[t];
    Pl[(bh * Uc + t) * KPc + kp] = lred[t];
  }
}

// ------------- combine partials -------------
// grid (B*H*U), block 64.
__global__ __launch_bounds__(64) void attn_combine(
    const float* __restrict__ Pm, const float* __restrict__ Pl,
    const float* __restrict__ Pctx, float* __restrict__ ctx) {
  const int gidx = blockIdx.x;   // bh*Uc + u
  const int t = threadIdx.x;     // d
  float M = -INFINITY;
#pragma unroll
  for (int p = 0; p < KPc; ++p) M = fmaxf(M, Pm[gidx * KPc + p]);
  float wgt[KPc];
  float L = 0.f;
#pragma unroll
  for (int p = 0; p < KPc; ++p) {
    wgt[p] = expf(Pm[gidx * KPc + p] - M);
    L += wgt[p] * Pl[gidx * KPc + p];
  }
  float acc = 0.f;
#pragma unroll
  for (int p = 0; p < KPc; ++p)
    acc += Pctx[((size_t)gidx * KPc + p) * DKc + t] * wgt[p];
  ctx[(size_t)gidx * DKc + t] = acc / L;
}

// ------------- sparse output projection -------------
__global__ __launch_bounds__(256) void output_kernel(
    const float* __restrict__ ctx, const int* __restrict__ idx,
    const int* __restrict__ flags, const float* __restrict__ wo,
    const float* __restrict__ bo, float* __restrict__ out) {
  const int t = threadIdx.x;
  const int l = blockIdx.x, b = blockIdx.y;
  float* orow = out + ((size_t)b * Lc + l) * Dc;
  if (flags[b * Lc + l] == 0) {
#pragma unroll
    for (int j = 0; j < 4; ++j) orow[t + j * 256] = bo[t + j * 256];
    return;
  }
  __shared__ float prow[Dc];
  __shared__ int mh[Hc], mu[Hc];
  __shared__ int nm;
#pragma unroll
  for (int j = 0; j < 4; ++j) prow[t + j * 256] = 0.f;
  if (t == 0) {
    int c = 0;
    for (int h = 0; h < Hc; ++h)
      for (int u = 0; u < Uc; ++u)
        if (idx[(b * Hc + h) * Uc + u] == l) { mh[c] = h; mu[c] = u; ++c; }
    nm = c;
  }
  __syncthreads();
  const int c = nm;
  for (int m = 0; m < c; ++m) {
    if (t < DKc) prow[mh[m] * DKc + t] = ctx[((b * Hc + mh[m]) * Uc + mu[m]) * DKc + t];
  }
  __syncthreads();
  float acc[4] = {0.f, 0.f, 0.f, 0.f};
  for (int m = 0; m < c; ++m) {
    const int dbase = mh[m] * DKc;
    for (int d = 0; d < DKc; d += 4) {
      float4 pv = *(const float4*)(prow + dbase + d);
#pragma unroll
      for (int j = 0; j < 4; ++j) {
        const int n = t + j * 256;
        float4 wv = *(const float4*)(wo + (size_t)n * Dc + dbase + d);
        acc[j] += pv.x * wv.x + pv.y * wv.y + pv.z * wv.z + pv.w * wv.w;
      }
    }
  }
#pragma unroll
  for (int j = 0; j < 4; ++j) {
    const int n = t + j * 256;
    orow[n] = acc[j] + bo[n];
  }
}

extern "C" void kernel_launch(void* const* d_in, const int* in_sizes, int n_in,
                              void* d_out, int out_size, void* d_ws, size_t ws_size,
                              hipStream_t stream) {
  const float* x  = (const float*)d_in[0];
  const float* wq = (const float*)d_in[1];
  const float* bq = (const float*)d_in[2];
  const float* wk = (const float*)d_in[3];
  const float* bk = (const float*)d_in[4];
  const float* wv = (const float*)d_in[5];
  const float* bv = (const float*)d_in[6];
  const float* wo = (const float*)d_in[7];
  const float* bo = (const float*)d_in[8];
  float* out = (float*)d_out;

  char* ws = (char*)d_ws;
  size_t off = 0;
  auto alloc = [&](size_t bytes) -> void* {
    void* p = ws + off;
    off += (bytes + 255) & ~(size_t)255;
    return p;
  };
  const size_t NE = (size_t)Bc * Lc * Dc;           // 8388608
  float* V   = (float*)alloc(sizeof(float) * NE);
  float* Mv  = (float*)alloc(sizeof(float) * (size_t)Bc * Hc * Lc);
  float* ctx = (float*)alloc(sizeof(float) * (size_t)Bc * Hc * Uc * DKc);
  int*   idx = (int*)alloc(sizeof(int) * (size_t)Bc * Hc * Uc);
  int*   flg = (int*)alloc(sizeof(int) * (size_t)Bc * Lc);
  _Float16* x1 = (_Float16*)alloc(2 * NE);
  _Float16* x2 = (_Float16*)alloc(2 * NE);
  _Float16* w1 = (_Float16*)alloc(2 * (size_t)Dc * Dc);
  _Float16* w2 = (_Float16*)alloc(2 * (size_t)Dc * Dc);
  _Float16* q1h = (_Float16*)alloc(2 * NE);
  _Float16* q2h = (_Float16*)alloc(2 * NE);
  _Float16* k1h = (_Float16*)alloc(2 * NE);
  _Float16* k2h = (_Float16*)alloc(2 * NE);
  float* Pm   = (float*)alloc(sizeof(float) * (size_t)Bc * Hc * Uc * KPc);
  float* Pl   = (float*)alloc(sizeof(float) * (size_t)Bc * Hc * Uc * KPc);
  float* Pctx = (float*)alloc(sizeof(float) * (size_t)Bc * Hc * Uc * KPc * DKc);

  const int M = Bc * Lc;                            // 8192
  split_plain<<<dim3(NE / 1024), 256, 0, stream>>>(x, x1, x2, (int)NE);
  const dim3 gp(M / 128, Dc / 128);                 // (64, 8)

  split_plain<<<dim3(Dc * Dc / 1024), 256, 0, stream>>>(wq, w1, w2, Dc * Dc);
  proj_mfma<1><<<gp, 256, 0, stream>>>(x1, x2, w1, w2, bq, nullptr, q1h, q2h, M, Dc, Dc);
  split_plain<<<dim3(Dc * Dc / 1024), 256, 0, stream>>>(wk, w1, w2, Dc * Dc);
  proj_mfma<1><<<gp, 256, 0, stream>>>(x1, x2, w1, w2, bk, nullptr, k1h, k2h, M, Dc, Dc);
  split_plain<<<dim3(Dc * Dc / 1024), 256, 0, stream>>>(wv, w1, w2, Dc * Dc);
  proj_mfma<0><<<gp, 256, 0, stream>>>(x1, x2, w1, w2, bv, V, nullptr, nullptr, M, Dc, Dc);

  rowmax_mfma<<<dim3(Bc * Hc, Lc / 128), 256, 0, stream>>>(q1h, q2h, k1h, k2h, Mv);

  zero_flags<<<dim3((Bc * Lc + 255) / 256), 256, 0, stream>>>(flg, Bc * Lc);
  topk_kernel<<<dim3(Hc, Bc), 256, 0, stream>>>(Mv, idx, flg);
  attn_part<<<dim3(KPc, Hc, Bc), 256, 0, stream>>>(q1h, q2h, k1h, k2h, V, idx, Pm, Pl, Pctx);
  attn_combine<<<dim3(Bc * Hc * Uc), 64, 0, stream>>>(Pm, Pl, Pctx, ctx);
  output_kernel<<<dim3(Lc, Bc), 256, 0, stream>>>(ctx, idx, flg, wo, bo, out);
}